// Round 6
// baseline (6103.584 us; speedup 1.0000x reference)
//
#include <hip/hip_runtime.h>
#include <hip/hip_cooperative_groups.h>

namespace cg = cooperative_groups;

#define B 128
#define S 16
#define E 512
#define R 1000
#define K3 1536
#define NW0 1920   // init worklist: 128 b * 15 pairs
#define NSLC 8     // K-slices for merged gemm (1000/8 = 125 exact)
#define GRID 256   // cooperative grid: 1 block/CU, co-residency guaranteed
#define SCALE 0.04419417382415922f

struct KParams {
  const int* tokens;
  const float *emb, *W_ih, *W_hh, *b_ih, *b_hh, *w_fc, *b_fc, *Wq, *bq, *Wk, *bk;
  float *X, *GI, *PAIR, *SCR, *H1C, *GHC, *KREL, *QK, *SP, *SC, *MROW, *PART, *LOSS;
  int *pos, *wlb, *wlL, *wlR, *xdst;
  float* out;
};

static __device__ __forceinline__ float sigm(float x) { return 1.f / (1.f + expf(-x)); }

static __device__ __forceinline__ float brsum(float v, float* sb) {
  int tid = threadIdx.x;
  sb[tid] = v; __syncthreads();
  for (int s = 128; s > 0; s >>= 1) {
    if (tid < s) sb[tid] += sb[tid + s];
    __syncthreads();
  }
  float r = sb[0]; __syncthreads();
  return r;
}
static __device__ __forceinline__ float brmax(float v, float* sb) {
  int tid = threadIdx.x;
  sb[tid] = v; __syncthreads();
  for (int s = 128; s > 0; s >>= 1) {
    if (tid < s) sb[tid] = fmaxf(sb[tid], sb[tid + s]);
    __syncthreads();
  }
  float r = sb[0]; __syncthreads();
  return r;
}

// ---------- tiled GEMM tile (64x64, K=512), register-prefetch double-buffered ----------
static __device__ void dev_gemm(int tX, int tY, const float* __restrict__ A, int strideB,
                                int M, const float* __restrict__ W1,
                                const float* __restrict__ W2, int N,
                                const float* __restrict__ b1, const float* __restrict__ b2,
                                float scale, float* __restrict__ C, int ldc,
                                const int* __restrict__ cdst,
                                float (*As)[64], float (*Ws)[64]) {
  int tid = threadIdx.x;
  int mBase = tY * 64, nBase = tX * 64;
  int tx = tid & 15, ty = tid >> 4;
  int li = tid & 63;
  int lk = (tid >> 6) * 4;
  float acc[4][4] = {{0.f,0.f,0.f,0.f},{0.f,0.f,0.f,0.f},{0.f,0.f,0.f,0.f},{0.f,0.f,0.f,0.f}};
  int m = mBase + li;
  const float* Arow = (m < M) ? (A + (size_t)m * strideB) : nullptr;
  int n = nBase + li;
  const float* Wrow = nullptr;
  if (n < N) Wrow = (W2 && n >= 512) ? (W2 + (size_t)(n - 512) * E) : (W1 + (size_t)n * E);

  float4 av = Arow ? *(const float4*)(Arow + lk) : make_float4(0.f, 0.f, 0.f, 0.f);
  float4 wv = Wrow ? *(const float4*)(Wrow + lk) : make_float4(0.f, 0.f, 0.f, 0.f);

  for (int k0 = 0; k0 < E; k0 += 16) {
    As[lk + 0][li] = av.x; As[lk + 1][li] = av.y;
    As[lk + 2][li] = av.z; As[lk + 3][li] = av.w;
    Ws[lk + 0][li] = wv.x; Ws[lk + 1][li] = wv.y;
    Ws[lk + 2][li] = wv.z; Ws[lk + 3][li] = wv.w;
    __syncthreads();
    if (k0 + 16 < E) {
      av = Arow ? *(const float4*)(Arow + k0 + 16 + lk) : make_float4(0.f, 0.f, 0.f, 0.f);
      wv = Wrow ? *(const float4*)(Wrow + k0 + 16 + lk) : make_float4(0.f, 0.f, 0.f, 0.f);
    }
#pragma unroll
    for (int k = 0; k < 16; ++k) {
      float4 a4 = *(const float4*)&As[k][ty * 4];
      float4 w4 = *(const float4*)&Ws[k][tx * 4];
      acc[0][0] = fmaf(a4.x, w4.x, acc[0][0]); acc[0][1] = fmaf(a4.x, w4.y, acc[0][1]);
      acc[0][2] = fmaf(a4.x, w4.z, acc[0][2]); acc[0][3] = fmaf(a4.x, w4.w, acc[0][3]);
      acc[1][0] = fmaf(a4.y, w4.x, acc[1][0]); acc[1][1] = fmaf(a4.y, w4.y, acc[1][1]);
      acc[1][2] = fmaf(a4.y, w4.z, acc[1][2]); acc[1][3] = fmaf(a4.y, w4.w, acc[1][3]);
      acc[2][0] = fmaf(a4.z, w4.x, acc[2][0]); acc[2][1] = fmaf(a4.z, w4.y, acc[2][1]);
      acc[2][2] = fmaf(a4.z, w4.z, acc[2][2]); acc[2][3] = fmaf(a4.z, w4.w, acc[2][3]);
      acc[3][0] = fmaf(a4.w, w4.x, acc[3][0]); acc[3][1] = fmaf(a4.w, w4.y, acc[3][1]);
      acc[3][2] = fmaf(a4.w, w4.z, acc[3][2]); acc[3][3] = fmaf(a4.w, w4.w, acc[3][3]);
    }
    __syncthreads();
  }
#pragma unroll
  for (int r = 0; r < 4; ++r) {
    int mm = mBase + ty * 4 + r;
    if (mm >= M) continue;
    size_t crow = (size_t)(cdst ? cdst[mm] : mm) * ldc;
#pragma unroll
    for (int c = 0; c < 4; ++c) {
      int nn = nBase + tx * 4 + c;
      if (nn >= N) continue;
      float v = acc[r][c] * scale;
      if (b1) v += (b2 && nn >= 512) ? b2[nn - 512] : b1[nn];
      C[crow + nn] = v;
    }
  }
}

static __device__ void dev_h1(int w, const KParams& P) {
  const float* gi = P.GI + (size_t)(P.wlb[w] * 16 + P.wlL[w]) * K3;
  float* h = P.H1C + (size_t)w * E;
  for (int e = threadIdx.x; e < E; e += 256) {
    float r = sigm(gi[e] + P.b_hh[e]);
    float z = sigm(gi[E + e] + P.b_hh[E + e]);
    float n = tanhf(gi[2 * E + e] + r * P.b_hh[2 * E + e]);
    h[e] = (1.f - z) * n;
  }
}

static __device__ void dev_pairc(int w, const KParams& P, float* sb) {
  int tid = threadIdx.x;
  int b = P.wlb[w], ls = P.wlL[w], rs = P.wlR[w];
  const float* gi = P.GI + (size_t)(b * 16 + rs) * K3;
  const float* gh = P.GHC + (size_t)w * K3;
  const float* h = P.H1C + (size_t)w * E;
  float* p = P.PAIR + (size_t)(b * 16 + ls) * E;
  float part = 0.f;
  for (int e = tid; e < E; e += 256) {
    float r = sigm(gi[e] + gh[e]);
    float z = sigm(gi[E + e] + gh[E + e]);
    float n = tanhf(gi[2 * E + e] + r * gh[2 * E + e]);
    float pv = (1.f - z) * n + z * h[e];
    p[e] = pv;
    part += pv * P.w_fc[e];
  }
  float d = brsum(part, sb);
  if (tid == 0) P.SCR[b * 16 + ls] = sigm(d + P.b_fc[0]);
}

static __device__ void dev_sel(int b, int Pn, const KParams& P, int* s_m) {
  int tid = threadIdx.x;
  if (tid == 0) {
    int L = Pn + 1;
    int lp[16];
    for (int i = 0; i < L; ++i) lp[i] = P.pos[b * 16 + i];
    float best = -1e30f; int sel = 0;
    for (int i = 0; i < Pn; ++i) {
      float v = P.SCR[b * 16 + lp[i]];
      if (v > best) { best = v; sel = i; }
    }
    int r1i = (sel + 2 < L) ? sel + 2 : L - 1;
    int l1 = lp[sel], r1 = lp[r1i];
    int l0 = (sel > 0) ? lp[sel - 1] : l1;
    int r0 = (sel > 0) ? lp[sel] : r1;
    P.wlb[2 * b] = b;     P.wlL[2 * b] = l0;     P.wlR[2 * b] = r0;
    P.wlb[2 * b + 1] = b; P.wlL[2 * b + 1] = l1; P.wlR[2 * b + 1] = r1;
    P.xdst[b] = b * 16 + lp[sel];
    for (int i = sel + 1; i < L - 1; ++i) P.pos[b * 16 + i] = lp[i + 1];
    *s_m = lp[sel];
  }
  __syncthreads();
  int ms = *s_m;
  const float* src = P.PAIR + (size_t)(b * 16 + ms) * E;
  float* dst = P.SP + (size_t)b * E;
  for (int e = tid; e < E; e += 256) dst[e] = src[e];
}

static __device__ void dev_softmax(int b, int t, int writeProb, const KParams& P, float* sb) {
  int tid = threadIdx.x;
  const float* q = P.QK + (size_t)b * 1024;
  const float* kl = q + 512;
  float part = 0.f;
  for (int e = tid; e < E; e += 256) part += q[e] * kl[e];
  float last = brsum(part, sb) * SCALE;
  float* s = P.SC + (size_t)b * (R + 1);
  if (tid == 0) s[R] = last;
  __syncthreads();
  float mx = -1e30f;
  for (int j = tid; j <= R; j += 256) mx = fmaxf(mx, s[j]);
  mx = brmax(mx, sb);
  float z = 0.f, s1 = 0.f;
  for (int j = tid; j <= R; j += 256) {
    float sj = s[j];
    float e = expf(sj - mx);
    z += e; s1 += e * sj;
  }
  z = brsum(z, sb);
  s1 = brsum(s1, sb);
  if (tid == 0) P.LOSS[b * 16 + t] = mx + logf(z) - s1 / z;
  if (writeProb) {
    float inv = 1.f / z;
    for (int j = tid; j <= R; j += 256) s[j] = expf(s[j] - mx) * inv;
    float pr = expf(last - mx) * inv;
    for (int e = tid; e < E; e += 256)
      P.MROW[(size_t)b * E + e] = pr * P.SP[(size_t)b * E + e];
  }
}

// merged split-K: tile = slice*16 + mT*8 + nT
static __device__ void dev_merged(int tile, const KParams& P, float (*As)[64], float (*Ws)[64]) {
  int tid = threadIdx.x;
  int slice = tile >> 4;
  int rem = tile & 15;
  int mBase = (rem >> 3) * 64;
  int nBase = (rem & 7) * 64;
  int kbeg = slice * 125, kend = kbeg + 125;
  int tx = tid & 15, ty = tid >> 4;
  int li = tid & 63;
  int lk = (tid >> 6) * 4;
  int wr = tid >> 6;
  float acc[4][4] = {{0.f,0.f,0.f,0.f},{0.f,0.f,0.f,0.f},{0.f,0.f,0.f,0.f},{0.f,0.f,0.f,0.f}};
  int m = mBase + li;
  for (int k0 = kbeg; k0 < kend; k0 += 16) {
    float a4[4];
#pragma unroll
    for (int j = 0; j < 4; ++j) {
      int kk = k0 + lk + j;
      a4[j] = (kk < kend) ? P.SC[(size_t)m * (R + 1) + kk] : 0.f;
    }
    As[lk + 0][li] = a4[0]; As[lk + 1][li] = a4[1];
    As[lk + 2][li] = a4[2]; As[lk + 3][li] = a4[3];
#pragma unroll
    for (int j = 0; j < 4; ++j) {
      int kk = k0 + wr * 4 + j;
      Ws[wr * 4 + j][li] = (kk < kend) ? P.emb[(size_t)kk * E + nBase + li] : 0.f;
    }
    __syncthreads();
#pragma unroll
    for (int k = 0; k < 16; ++k) {
      float4 av = *(const float4*)&As[k][ty * 4];
      float4 wv = *(const float4*)&Ws[k][tx * 4];
      acc[0][0] = fmaf(av.x, wv.x, acc[0][0]); acc[0][1] = fmaf(av.x, wv.y, acc[0][1]);
      acc[0][2] = fmaf(av.x, wv.z, acc[0][2]); acc[0][3] = fmaf(av.x, wv.w, acc[0][3]);
      acc[1][0] = fmaf(av.y, wv.x, acc[1][0]); acc[1][1] = fmaf(av.y, wv.y, acc[1][1]);
      acc[1][2] = fmaf(av.y, wv.z, acc[1][2]); acc[1][3] = fmaf(av.y, wv.w, acc[1][3]);
      acc[2][0] = fmaf(av.z, wv.x, acc[2][0]); acc[2][1] = fmaf(av.z, wv.y, acc[2][1]);
      acc[2][2] = fmaf(av.z, wv.z, acc[2][2]); acc[2][3] = fmaf(av.z, wv.w, acc[2][3]);
      acc[3][0] = fmaf(av.w, wv.x, acc[3][0]); acc[3][1] = fmaf(av.w, wv.y, acc[3][1]);
      acc[3][2] = fmaf(av.w, wv.z, acc[3][2]); acc[3][3] = fmaf(av.w, wv.w, acc[3][3]);
    }
    __syncthreads();
  }
  float* pt = P.PART + ((size_t)slice * B) * E;
#pragma unroll
  for (int r = 0; r < 4; ++r) {
    int mm = mBase + ty * 4 + r;
#pragma unroll
    for (int c = 0; c < 4; ++c) {
      int nn = nBase + tx * 4 + c;
      pt[(size_t)mm * E + nn] = acc[r][c];
    }
  }
}

static __device__ void dev_red(int m, const KParams& P) {
  for (int n = threadIdx.x; n < E; n += 256) {
    float v = P.MROW[(size_t)m * E + n];
#pragma unroll
    for (int s = 0; s < NSLC; ++s) v += P.PART[((size_t)s * B + m) * E + n];
    P.MROW[(size_t)m * E + n] = v;
  }
}

__global__ __launch_bounds__(256, 1) void k_all(KParams P) {
  cg::grid_group grid = cg::this_grid();
  __shared__ float As[16][64];
  __shared__ float Ws[16][64];
  __shared__ float sb[256];
  __shared__ int si;
  const int bid = blockIdx.x;
  const int tid = threadIdx.x;

  // P0: embed gather + pos/worklist init
  for (int idx = bid * 256 + tid; idx < B * S * E; idx += GRID * 256) {
    int row = idx >> 9, e = idx & (E - 1);
    P.X[idx] = P.emb[(size_t)P.tokens[row] * E + e];
  }
  for (int idx = bid * 256 + tid; idx < B * 16; idx += GRID * 256) P.pos[idx] = idx & 15;
  for (int idx = bid * 256 + tid; idx < NW0; idx += GRID * 256) {
    P.wlb[idx] = idx / 15; P.wlL[idx] = idx % 15; P.wlR[idx] = idx % 15 + 1;
  }
  grid.sync();

  // P1: KREL (128 tiles) + full GI (768 tiles)
  for (int tile = bid; tile < 128 + 768; tile += GRID) {
    if (tile < 128)
      dev_gemm(tile & 7, tile >> 3, P.emb, E, R, P.Wk, nullptr, E, P.bk, nullptr, 1.f,
               P.KREL, E, nullptr, As, Ws);
    else {
      int q = tile - 128;
      dev_gemm(q % 24, q / 24, P.X, E, B * 16, P.W_ih, nullptr, K3, P.b_ih, nullptr, 1.f,
               P.GI, K3, nullptr, As, Ws);
    }
  }
  grid.sync();
  // P2: h1 init (1920)
  for (int w = bid; w < NW0; w += GRID) dev_h1(w, P);
  grid.sync();
  // P3: GH init (24 x 30 tiles)
  for (int tile = bid; tile < 24 * 30; tile += GRID)
    dev_gemm(tile % 24, tile / 24, P.H1C, E, NW0, P.W_hh, nullptr, K3, P.b_hh, nullptr, 1.f,
             P.GHC, K3, nullptr, As, Ws);
  grid.sync();
  // P4: pair init (1920)
  for (int w = bid; w < NW0; w += GRID) dev_pairc(w, P, sb);
  grid.sync();

  // ---- 14 merge steps ----
  for (int t = 0; t < 14; ++t) {
    for (int b = bid; b < B; b += GRID) dev_sel(b, 15 - t, P, &si);
    grid.sync();
    for (int tile = bid; tile < 32; tile += GRID)
      dev_gemm(tile & 15, tile >> 4, P.SP, E, B, P.Wq, P.Wk, 1024, P.bq, P.bk, 1.f,
               P.QK, 1024, nullptr, As, Ws);
    grid.sync();
    for (int tile = bid; tile < 32; tile += GRID)
      dev_gemm(tile & 15, tile >> 4, P.QK, 1024, B, P.KREL, nullptr, R, nullptr, nullptr,
               SCALE, P.SC, R + 1, nullptr, As, Ws);
    grid.sync();
    for (int b = bid; b < B; b += GRID) dev_softmax(b, t, 1, P, sb);
    grid.sync();
    for (int tile = bid; tile < 128; tile += GRID) dev_merged(tile, P, As, Ws);
    grid.sync();
    for (int m = bid; m < B; m += GRID) dev_red(m, P);
    grid.sync();
    for (int tile = bid; tile < 48; tile += GRID)
      dev_gemm(tile % 24, tile / 24, P.MROW, E, B, P.W_ih, nullptr, K3, P.b_ih, nullptr, 1.f,
               P.GI, K3, P.xdst, As, Ws);
    grid.sync();
    for (int w = bid; w < 256; w += GRID) dev_h1(w, P);
    grid.sync();
    for (int tile = bid; tile < 96; tile += GRID)
      dev_gemm(tile % 24, tile / 24, P.H1C, E, 256, P.W_hh, nullptr, K3, P.b_hh, nullptr, 1.f,
               P.GHC, K3, nullptr, As, Ws);
    grid.sync();
    for (int w = bid; w < 256; w += GRID) dev_pairc(w, P, sb);
    grid.sync();
  }

  // ---- final: L==2 branch + attention + writeout ----
  for (int b = bid; b < B; b += GRID) {
    const float* src = P.PAIR + (size_t)(b * 16 + P.pos[b * 16]) * E;
    float* dst = P.SP + (size_t)b * E;
    for (int e = tid; e < E; e += 256) dst[e] = src[e];
  }
  grid.sync();
  for (int tile = bid; tile < 32; tile += GRID)
    dev_gemm(tile & 15, tile >> 4, P.SP, E, B, P.Wq, P.Wk, 1024, P.bq, P.bk, 1.f,
             P.QK, 1024, nullptr, As, Ws);
  grid.sync();
  for (int tile = bid; tile < 32; tile += GRID)
    dev_gemm(tile & 15, tile >> 4, P.QK, 1024, B, P.KREL, nullptr, R, nullptr, nullptr,
             SCALE, P.SC, R + 1, nullptr, As, Ws);
  grid.sync();
  for (int b = bid; b < B; b += GRID) dev_softmax(b, 15, 0, P, sb);
  grid.sync();
  for (int idx = bid * 256 + tid; idx < B * (R + 1) + B * 16; idx += GRID * 256) {
    const int NS = B * (R + 1);
    if (idx < NS) P.out[idx] = P.SC[idx];
    else {
      int r = idx - NS;
      int tt = r & 15;
      P.out[idx] = (tt == 14) ? 0.f : P.LOSS[r];
    }
  }
}

extern "C" void kernel_launch(void* const* d_in, const int* in_sizes, int n_in,
                              void* d_out, int out_size, void* d_ws, size_t ws_size,
                              hipStream_t stream) {
  (void)in_sizes; (void)n_in; (void)out_size; (void)ws_size;
  KParams p;
  p.tokens = (const int*)d_in[0];
  p.emb = (const float*)d_in[1];
  p.W_ih = (const float*)d_in[2];
  p.W_hh = (const float*)d_in[3];
  p.b_ih = (const float*)d_in[4];
  p.b_hh = (const float*)d_in[5];
  p.w_fc = (const float*)d_in[6];
  p.b_fc = (const float*)d_in[7];
  p.Wq = (const float*)d_in[8];
  p.bq = (const float*)d_in[9];
  p.Wk = (const float*)d_in[10];
  p.bk = (const float*)d_in[11];
  p.out = (float*)d_out;

  float* ws = (float*)d_ws;
  size_t o = 0;
  p.X = ws + o;     o += (size_t)B * 16 * E;
  p.GI = ws + o;    o += (size_t)B * 16 * K3;
  p.PAIR = ws + o;  o += (size_t)B * 16 * E;
  p.SCR = ws + o;   o += (size_t)B * 16;
  p.H1C = ws + o;   o += (size_t)NW0 * E;
  p.GHC = ws + o;   o += (size_t)NW0 * K3;
  p.KREL = ws + o;  o += (size_t)R * E;
  p.QK = ws + o;    o += (size_t)B * 1024;
  p.SP = ws + o;    o += (size_t)B * E;
  p.SC = ws + o;    o += (size_t)B * (R + 1);
  p.MROW = ws + o;  o += (size_t)B * E;
  p.PART = ws + o;  o += (size_t)NSLC * B * E;
  p.LOSS = ws + o;  o += (size_t)B * 16;
  p.pos = (int*)(ws + o);  o += B * 16;
  p.wlb = (int*)(ws + o);  o += NW0;
  p.wlL = (int*)(ws + o);  o += NW0;
  p.wlR = (int*)(ws + o);  o += NW0;
  p.xdst = (int*)(ws + o); o += B;

  void* kargs[] = {(void*)&p};
  hipLaunchCooperativeKernel((const void*)k_all, dim3(GRID), dim3(256), kargs, 0, stream);
}

// Round 7
// 3310.104 us; speedup vs baseline: 1.8439x; 1.8439x over previous
//
#include <hip/hip_runtime.h>

#define B 128
#define S 16
#define E 512
#define R 1000
#define K3 1536
#define NW0 1920   // init worklist: 128 b * 15 pairs
#define NSLC 8     // K-slices for merged gemm (1000/8 = 125 exact)
#define SCALE 0.04419417382415922f

static __device__ __forceinline__ float sigm(float x) { return 1.f / (1.f + expf(-x)); }
// h1 of left token: identical expression to R5 (bit-identical results)
static __device__ __forceinline__ float h1f(float g0, float g1, float g2,
                                            float b0, float b1, float b2) {
  float r = sigm(g0 + b0);
  float z = sigm(g1 + b1);
  float n = tanhf(g2 + r * b2);
  return (1.f - z) * n;
}
static __device__ __forceinline__ float4 f40() { return make_float4(0.f, 0.f, 0.f, 0.f); }

static __device__ __forceinline__ float brsum(float v, float* sb) {
  int tid = threadIdx.x;
  sb[tid] = v; __syncthreads();
  for (int s = 128; s > 0; s >>= 1) {
    if (tid < s) sb[tid] += sb[tid + s];
    __syncthreads();
  }
  float r = sb[0]; __syncthreads();
  return r;
}
static __device__ __forceinline__ float brmax(float v, float* sb) {
  int tid = threadIdx.x;
  sb[tid] = v; __syncthreads();
  for (int s = 128; s > 0; s >>= 1) {
    if (tid < s) sb[tid] = fmaxf(sb[tid], sb[tid + s]);
    __syncthreads();
  }
  float r = sb[0]; __syncthreads();
  return r;
}

static __device__ __forceinline__ void fma16(const float (*__restrict__ As)[64],
                                             const float (*__restrict__ Ws)[64],
                                             float acc[4][4], int tx, int ty) {
#pragma unroll
  for (int k = 0; k < 16; ++k) {
    float4 a4 = *(const float4*)&As[k][ty * 4];
    float4 w4 = *(const float4*)&Ws[k][tx * 4];
    acc[0][0] = fmaf(a4.x, w4.x, acc[0][0]); acc[0][1] = fmaf(a4.x, w4.y, acc[0][1]);
    acc[0][2] = fmaf(a4.x, w4.z, acc[0][2]); acc[0][3] = fmaf(a4.x, w4.w, acc[0][3]);
    acc[1][0] = fmaf(a4.y, w4.x, acc[1][0]); acc[1][1] = fmaf(a4.y, w4.y, acc[1][1]);
    acc[1][2] = fmaf(a4.y, w4.z, acc[1][2]); acc[1][3] = fmaf(a4.y, w4.w, acc[1][3]);
    acc[2][0] = fmaf(a4.z, w4.x, acc[2][0]); acc[2][1] = fmaf(a4.z, w4.y, acc[2][1]);
    acc[2][2] = fmaf(a4.z, w4.z, acc[2][2]); acc[2][3] = fmaf(a4.z, w4.w, acc[2][3]);
    acc[3][0] = fmaf(a4.w, w4.x, acc[3][0]); acc[3][1] = fmaf(a4.w, w4.y, acc[3][1]);
    acc[3][2] = fmaf(a4.w, w4.z, acc[3][2]); acc[3][3] = fmaf(a4.w, w4.w, acc[3][3]);
  }
}

// ---------- embed + init worklist ----------
__global__ __launch_bounds__(256) void k_embed(const int* __restrict__ tokens,
                                               const float* __restrict__ emb,
                                               float* __restrict__ X) {
  int idx = blockIdx.x * 256 + threadIdx.x;
  if (idx >= B * S * E) return;
  int row = idx >> 9, e = idx & (E - 1);
  X[idx] = emb[(size_t)tokens[row] * E + e];
}
__global__ __launch_bounds__(256) void k_initwl(int* __restrict__ pos,
                                                int* __restrict__ wlb,
                                                int* __restrict__ wlL,
                                                int* __restrict__ wlR) {
  int idx = blockIdx.x * 256 + threadIdx.x;
  if (idx < B * 16) pos[idx] = idx & 15;
  if (idx < NW0) {
    wlb[idx] = idx / 15; wlL[idx] = idx % 15; wlR[idx] = idx % 15 + 1;
  }
}

// ---------- standard init GEMM: C[m,n] = sum_k A[m*strideB+k]*W[n*E+k] + bias[n]
__global__ __launch_bounds__(256) void k_gemm(const float* __restrict__ A, int strideB, int M,
                                              const float* __restrict__ W, int N,
                                              const float* __restrict__ bias,
                                              float* __restrict__ C, int ldc) {
  __shared__ float As[16][64], Ws[16][64];
  int tid = threadIdx.x, mBase = blockIdx.y * 64, nBase = blockIdx.x * 64;
  int tx = tid & 15, ty = tid >> 4, li = tid & 63, lk = (tid >> 6) * 4;
  float acc[4][4] = {};
  int m = mBase + li;
  const float* Arow = (m < M) ? A + (size_t)m * strideB : nullptr;
  int n = nBase + li;
  const float* Wrow = (n < N) ? W + (size_t)n * E : nullptr;
  float4 av = Arow ? *(const float4*)(Arow + lk) : f40();
  float4 wv = Wrow ? *(const float4*)(Wrow + lk) : f40();
  for (int k0 = 0; k0 < E; k0 += 16) {
    As[lk + 0][li] = av.x; As[lk + 1][li] = av.y; As[lk + 2][li] = av.z; As[lk + 3][li] = av.w;
    Ws[lk + 0][li] = wv.x; Ws[lk + 1][li] = wv.y; Ws[lk + 2][li] = wv.z; Ws[lk + 3][li] = wv.w;
    __syncthreads();
    if (k0 + 16 < E) {
      av = Arow ? *(const float4*)(Arow + k0 + 16 + lk) : f40();
      wv = Wrow ? *(const float4*)(Wrow + k0 + 16 + lk) : f40();
    }
    fma16(As, Ws, acc, tx, ty);
    __syncthreads();
  }
#pragma unroll
  for (int r = 0; r < 4; ++r) {
    int mm = mBase + ty * 4 + r;
    if (mm >= M) continue;
#pragma unroll
    for (int c = 0; c < 4; ++c) {
      int nn = nBase + tx * 4 + c;
      if (nn >= N) continue;
      C[(size_t)mm * ldc + nn] = acc[r][c] + (bias ? bias[nn] : 0.f);
    }
  }
}

// ---------- WQKT = KREL @ Wq (W k-major [K=512, N=512]) ----------
__global__ __launch_bounds__(256) void k_nt(const float* __restrict__ A, int M,
                                            const float* __restrict__ W,
                                            float* __restrict__ C) {
  __shared__ float As[16][64], Ws[16][64];
  int tid = threadIdx.x, mBase = blockIdx.y * 64, nBase = blockIdx.x * 64;
  int tx = tid & 15, ty = tid >> 4, li = tid & 63, lk = (tid >> 6) * 4;
  int wr = tid >> 6;
  float acc[4][4] = {};
  int m = mBase + li;
  const float* Arow = (m < M) ? A + (size_t)m * E : nullptr;
  for (int k0 = 0; k0 < E; k0 += 16) {
    float4 av = Arow ? *(const float4*)(Arow + k0 + lk) : f40();
    As[lk + 0][li] = av.x; As[lk + 1][li] = av.y; As[lk + 2][li] = av.z; As[lk + 3][li] = av.w;
#pragma unroll
    for (int j = 0; j < 4; ++j)
      Ws[wr * 4 + j][li] = W[(size_t)(k0 + wr * 4 + j) * E + nBase + li];
    __syncthreads();
    fma16(As, Ws, acc, tx, ty);
    __syncthreads();
  }
#pragma unroll
  for (int r = 0; r < 4; ++r) {
    int mm = mBase + ty * 4 + r;
    if (mm >= M) continue;
#pragma unroll
    for (int c = 0; c < 4; ++c)
      C[(size_t)mm * E + nBase + tx * 4 + c] = acc[r][c];
  }
}

// ---------- G = Wq^T @ Wk: C[m,n] = sum_f Wq[f,m]*Wk[f,n] (both k-major) ----------
__global__ __launch_bounds__(256) void k_tt(const float* __restrict__ A,
                                            const float* __restrict__ Bw,
                                            float* __restrict__ C) {
  __shared__ float As[16][64], Ws[16][64];
  int tid = threadIdx.x, mBase = blockIdx.y * 64, nBase = blockIdx.x * 64;
  int tx = tid & 15, ty = tid >> 4, li = tid & 63;
  int wr = tid >> 6;
  float acc[4][4] = {};
  for (int k0 = 0; k0 < E; k0 += 16) {
#pragma unroll
    for (int j = 0; j < 4; ++j) {
      As[wr * 4 + j][li] = A[(size_t)(k0 + wr * 4 + j) * E + mBase + li];
      Ws[wr * 4 + j][li] = Bw[(size_t)(k0 + wr * 4 + j) * E + nBase + li];
    }
    __syncthreads();
    fma16(As, Ws, acc, tx, ty);
    __syncthreads();
  }
#pragma unroll
  for (int r = 0; r < 4; ++r)
#pragma unroll
    for (int c = 0; c < 4; ++c)
      C[(size_t)(mBase + ty * 4 + r) * E + nBase + tx * 4 + c] = acc[r][c];
}

// ---------- small folded biases: cqu[0..999]=S*bq·KREL_j, cqu[1000+e]=S*(bq^T Wk + bk^T Wq)[e],
//            cqu[1512]=S*bq·bk ----------
__global__ __launch_bounds__(256) void k_smalls(const float* __restrict__ KREL,
                                                const float* __restrict__ Wq,
                                                const float* __restrict__ Wk,
                                                const float* __restrict__ bq,
                                                const float* __restrict__ bk,
                                                float* __restrict__ CQU) {
  __shared__ float sb[256];
  int bid = blockIdx.x, tid = threadIdx.x;
  if (bid < 4) {
    int j = bid * 256 + tid;
    if (j < R) {
      float s = 0.f;
      const float* kr = KREL + (size_t)j * E;
      for (int f = 0; f < E; ++f) s += bq[f] * kr[f];
      CQU[j] = SCALE * s;
    }
  } else if (bid < 6) {
    int e = (bid - 4) * 256 + tid;
    float s = 0.f;
    for (int f = 0; f < E; ++f) s += bq[f] * Wk[(size_t)f * E + e] + bk[f] * Wq[(size_t)f * E + e];
    CQU[1000 + e] = SCALE * s;
  } else {
    float part = 0.f;
    for (int f = tid; f < E; f += 256) part += bq[f] * bk[f];
    float s = brsum(part, sb);
    if (tid == 0) CQU[1512] = SCALE * s;
  }
}

// ---------- GH gemm with h1 fused into A-stage: GHC[w] = h1(GI[wl(w)]) @ Whh^T + bhh
__global__ __launch_bounds__(256) void k_gh(const float* __restrict__ GI,
                                            const int* __restrict__ wlb,
                                            const int* __restrict__ wlL, int M,
                                            const float* __restrict__ Whh,
                                            const float* __restrict__ bhh,
                                            float* __restrict__ GHC) {
  __shared__ float As[16][64], Ws[16][64];
  int tid = threadIdx.x, mBase = blockIdx.y * 64, nBase = blockIdx.x * 64;
  int tx = tid & 15, ty = tid >> 4, li = tid & 63, lk = (tid >> 6) * 4;
  float acc[4][4] = {};
  int m = mBase + li;
  const float* gi = (m < M) ? GI + (size_t)(wlb[m] * 16 + wlL[m]) * K3 : nullptr;
  const float* Wrow = Whh + (size_t)(nBase + li) * E;  // N=1536 exact
  for (int k0 = 0; k0 < E; k0 += 16) {
    float4 h = f40();
    if (gi) {
      float4 g0 = *(const float4*)(gi + k0 + lk);
      float4 g1 = *(const float4*)(gi + E + k0 + lk);
      float4 g2 = *(const float4*)(gi + 2 * E + k0 + lk);
      float4 c0 = *(const float4*)(bhh + k0 + lk);
      float4 c1 = *(const float4*)(bhh + E + k0 + lk);
      float4 c2 = *(const float4*)(bhh + 2 * E + k0 + lk);
      h.x = h1f(g0.x, g1.x, g2.x, c0.x, c1.x, c2.x);
      h.y = h1f(g0.y, g1.y, g2.y, c0.y, c1.y, c2.y);
      h.z = h1f(g0.z, g1.z, g2.z, c0.z, c1.z, c2.z);
      h.w = h1f(g0.w, g1.w, g2.w, c0.w, c1.w, c2.w);
    }
    As[lk + 0][li] = h.x; As[lk + 1][li] = h.y; As[lk + 2][li] = h.z; As[lk + 3][li] = h.w;
    float4 wv = *(const float4*)(Wrow + k0 + lk);
    Ws[lk + 0][li] = wv.x; Ws[lk + 1][li] = wv.y; Ws[lk + 2][li] = wv.z; Ws[lk + 3][li] = wv.w;
    __syncthreads();
    fma16(As, Ws, acc, tx, ty);
    __syncthreads();
  }
#pragma unroll
  for (int r = 0; r < 4; ++r) {
    int mm = mBase + ty * 4 + r;
    if (mm >= M) continue;
#pragma unroll
    for (int c = 0; c < 4; ++c) {
      int nn = nBase + tx * 4 + c;
      GHC[(size_t)mm * K3 + nn] = acc[r][c] + bhh[nn];
    }
  }
}

// ---------- GI step gemm: A = sum_s PART[s]; C row = xdst[m] ----------
__global__ __launch_bounds__(256) void k_gi(const float* __restrict__ PART,
                                            const float* __restrict__ Wih,
                                            const float* __restrict__ bih,
                                            const int* __restrict__ xdst,
                                            float* __restrict__ GI) {
  __shared__ float As[16][64], Ws[16][64];
  int tid = threadIdx.x, mBase = blockIdx.y * 64, nBase = blockIdx.x * 64;
  int tx = tid & 15, ty = tid >> 4, li = tid & 63, lk = (tid >> 6) * 4;
  float acc[4][4] = {};
  int m = mBase + li;  // < 128 always
  const float* Wrow = Wih + (size_t)(nBase + li) * E;  // N=1536 exact
  for (int k0 = 0; k0 < E; k0 += 16) {
    float4 a = f40();
#pragma unroll
    for (int s = 0; s < NSLC; ++s) {
      float4 p = *(const float4*)(PART + ((size_t)(s * B + m)) * E + k0 + lk);
      a.x += p.x; a.y += p.y; a.z += p.z; a.w += p.w;
    }
    As[lk + 0][li] = a.x; As[lk + 1][li] = a.y; As[lk + 2][li] = a.z; As[lk + 3][li] = a.w;
    float4 wv = *(const float4*)(Wrow + k0 + lk);
    Ws[lk + 0][li] = wv.x; Ws[lk + 1][li] = wv.y; Ws[lk + 2][li] = wv.z; Ws[lk + 3][li] = wv.w;
    __syncthreads();
    fma16(As, Ws, acc, tx, ty);
    __syncthreads();
  }
#pragma unroll
  for (int r = 0; r < 4; ++r) {
    size_t crow = (size_t)xdst[mBase + ty * 4 + r] * K3;
#pragma unroll
    for (int c = 0; c < 4; ++c) {
      int nn = nBase + tx * 4 + c;
      GI[crow + nn] = acc[r][c] + bih[nn];
    }
  }
}

// ---------- fused attention gemm: cols 0..999 -> SC (scores), 1000..1511 -> Y ----------
__global__ __launch_bounds__(256) void k_att(const float* __restrict__ SP,
                                             const float* __restrict__ WQKT,
                                             const float* __restrict__ GT,
                                             const float* __restrict__ CQU,
                                             float* __restrict__ SC,
                                             float* __restrict__ Y) {
  __shared__ float As[16][64], Ws[16][64];
  int tid = threadIdx.x, mBase = blockIdx.y * 64, nBase = blockIdx.x * 64;
  int tx = tid & 15, ty = tid >> 4, li = tid & 63, lk = (tid >> 6) * 4;
  float acc[4][4] = {};
  int m = mBase + li;  // < 128
  const float* Arow = SP + (size_t)m * E;
  int n = nBase + li;
  const float* Wrow = (n < 1000) ? WQKT + (size_t)n * E
                                 : (n < 1512 ? GT + (size_t)(n - 1000) * E : nullptr);
  float4 av = *(const float4*)(Arow + lk);
  float4 wv = Wrow ? *(const float4*)(Wrow + lk) : f40();
  for (int k0 = 0; k0 < E; k0 += 16) {
    As[lk + 0][li] = av.x; As[lk + 1][li] = av.y; As[lk + 2][li] = av.z; As[lk + 3][li] = av.w;
    Ws[lk + 0][li] = wv.x; Ws[lk + 1][li] = wv.y; Ws[lk + 2][li] = wv.z; Ws[lk + 3][li] = wv.w;
    __syncthreads();
    if (k0 + 16 < E) {
      av = *(const float4*)(Arow + k0 + 16 + lk);
      wv = Wrow ? *(const float4*)(Wrow + k0 + 16 + lk) : f40();
    }
    fma16(As, Ws, acc, tx, ty);
    __syncthreads();
  }
#pragma unroll
  for (int r = 0; r < 4; ++r) {
    int mm = mBase + ty * 4 + r;
#pragma unroll
    for (int c = 0; c < 4; ++c) {
      int nn = nBase + tx * 4 + c;
      if (nn >= 1512) continue;
      float v = acc[r][c] * SCALE + CQU[nn];
      if (nn < 1000) SC[(size_t)mm * (R + 1) + nn] = v;
      else Y[(size_t)mm * E + (nn - 1000)] = v;
    }
  }
}

// ---------- softmax / entropy; probs in place ----------
__global__ __launch_bounds__(256) void k_sm(float* __restrict__ SC,
                                            const float* __restrict__ Y,
                                            const float* __restrict__ SP,
                                            const float* __restrict__ CQU,
                                            float* __restrict__ LOSS, int t, int writeProb) {
  __shared__ float sb[256];
  int b = blockIdx.x, tid = threadIdx.x;
  const float* y = Y + (size_t)b * E;
  const float* sp = SP + (size_t)b * E;
  float part = 0.f;
  for (int e = tid; e < E; e += 256) part += y[e] * sp[e];
  float last = brsum(part, sb) + CQU[1512];
  float* s = SC + (size_t)b * (R + 1);
  if (tid == 0) s[R] = last;
  __syncthreads();
  float mx = -1e30f;
  for (int j = tid; j <= R; j += 256) mx = fmaxf(mx, s[j]);
  mx = brmax(mx, sb);
  float z = 0.f, s1 = 0.f;
  for (int j = tid; j <= R; j += 256) {
    float sj = s[j];
    float e = expf(sj - mx);
    z += e; s1 += e * sj;
  }
  z = brsum(z, sb);
  s1 = brsum(s1, sb);
  if (tid == 0) LOSS[b * 16 + t] = mx + logf(z) - s1 / z;
  if (writeProb) {
    float inv = 1.f / z;
    for (int j = tid; j <= R; j += 256) s[j] = expf(s[j] - mx) * inv;
  }
}

// ---------- merged split-K; slice 0 folds in probR*SP base ----------
__global__ __launch_bounds__(256) void k_mg(const float* __restrict__ SC,
                                            const float* __restrict__ emb,
                                            const float* __restrict__ SP,
                                            float* __restrict__ PART) {
  __shared__ float As[16][64], Ws[16][64];
  int tid = threadIdx.x;
  int nBase = blockIdx.x * 64, mBase = blockIdx.y * 64, slice = blockIdx.z;
  int kbeg = slice * 125, kend = kbeg + 125;
  int tx = tid & 15, ty = tid >> 4, li = tid & 63, lk = (tid >> 6) * 4;
  int wr = tid >> 6;
  float acc[4][4] = {};
  int m = mBase + li;
  for (int k0 = kbeg; k0 < kend; k0 += 16) {
    float a4[4];
#pragma unroll
    for (int j = 0; j < 4; ++j) {
      int kk = k0 + lk + j;
      a4[j] = (kk < kend) ? SC[(size_t)m * (R + 1) + kk] : 0.f;
    }
    As[lk + 0][li] = a4[0]; As[lk + 1][li] = a4[1]; As[lk + 2][li] = a4[2]; As[lk + 3][li] = a4[3];
#pragma unroll
    for (int j = 0; j < 4; ++j) {
      int kk = k0 + wr * 4 + j;
      Ws[wr * 4 + j][li] = (kk < kend) ? emb[(size_t)kk * E + nBase + li] : 0.f;
    }
    __syncthreads();
    fma16(As, Ws, acc, tx, ty);
    __syncthreads();
  }
  float* pt = PART + (size_t)slice * B * E;
#pragma unroll
  for (int r = 0; r < 4; ++r) {
    int mm = mBase + ty * 4 + r;
    float probR = (slice == 0) ? SC[(size_t)mm * (R + 1) + R] : 0.f;
#pragma unroll
    for (int c = 0; c < 4; ++c) {
      int nn = nBase + tx * 4 + c;
      float v = acc[r][c];
      if (slice == 0) v += probR * SP[(size_t)mm * E + nn];
      pt[(size_t)mm * E + nn] = v;
    }
  }
}

// ---------- pair body (h1 recomputed inline — identical bits to GH A-stage) ----------
static __device__ void dev_pair(int w, const int* wlb, const int* wlL, const int* wlR,
                                const float* GI, const float* GHC, const float* bhh,
                                const float* wfc, float bfc0,
                                float* PAIR, float* SCR, float* sb) {
  int tid = threadIdx.x;
  int b = wlb[w], ls = wlL[w], rs = wlR[w];
  const float* gil = GI + (size_t)(b * 16 + ls) * K3;
  const float* gir = GI + (size_t)(b * 16 + rs) * K3;
  const float* gh = GHC + (size_t)w * K3;
  float* p = PAIR + (size_t)(b * 16 + ls) * E;
  float part = 0.f;
  for (int e = tid; e < E; e += 256) {
    float h = h1f(gil[e], gil[E + e], gil[2 * E + e], bhh[e], bhh[E + e], bhh[2 * E + e]);
    float r = sigm(gir[e] + gh[e]);
    float z = sigm(gir[E + e] + gh[E + e]);
    float n = tanhf(gir[2 * E + e] + r * gh[2 * E + e]);
    float pv = (1.f - z) * n + z * h;
    p[e] = pv;
    part += pv * wfc[e];
  }
  float d = brsum(part, sb);
  if (tid == 0) SCR[b * 16 + ls] = sigm(d + bfc0);
}

static __device__ void dev_sel(int b, int Pn, const float* SCR, const float* PAIR,
                               int* pos, float* SP, int* xdst,
                               int* wlb, int* wlL, int* wlR, int* s_m) {
  int tid = threadIdx.x;
  if (tid == 0) {
    int L = Pn + 1;
    int lp[16];
    for (int i = 0; i < L; ++i) lp[i] = pos[b * 16 + i];
    float best = -1e30f; int sel = 0;
    for (int i = 0; i < Pn; ++i) {
      float v = SCR[b * 16 + lp[i]];
      if (v > best) { best = v; sel = i; }
    }
    int r1i = (sel + 2 < L) ? sel + 2 : L - 1;
    int l1 = lp[sel], r1 = lp[r1i];
    int l0 = (sel > 0) ? lp[sel - 1] : l1;
    int r0 = (sel > 0) ? lp[sel] : r1;
    wlb[2 * b] = b;     wlL[2 * b] = l0;     wlR[2 * b] = r0;
    wlb[2 * b + 1] = b; wlL[2 * b + 1] = l1; wlR[2 * b + 1] = r1;
    xdst[b] = b * 16 + lp[sel];
    for (int i = sel + 1; i < L - 1; ++i) pos[b * 16 + i] = lp[i + 1];
    *s_m = lp[sel];
  }
  __syncthreads();
  int ms = *s_m;
  const float* src = PAIR + (size_t)(b * 16 + ms) * E;
  float* dst = SP + (size_t)b * E;
  for (int e = tid; e < E; e += 256) dst[e] = src[e];
}

// init pairs (1920-wide)
__global__ __launch_bounds__(256) void k_pairc0(const int* __restrict__ wlb,
                                                const int* __restrict__ wlL,
                                                const int* __restrict__ wlR,
                                                const float* __restrict__ GI,
                                                const float* __restrict__ GHC,
                                                const float* __restrict__ bhh,
                                                const float* __restrict__ wfc,
                                                const float* __restrict__ bfc,
                                                float* __restrict__ PAIR,
                                                float* __restrict__ SCR) {
  __shared__ float sb[256];
  dev_pair(blockIdx.x, wlb, wlL, wlR, GI, GHC, bhh, wfc, bfc[0], PAIR, SCR, sb);
}

// first sel (P=15)
__global__ __launch_bounds__(256) void k_sel0(const float* __restrict__ SCR,
                                              const float* __restrict__ PAIR,
                                              int* __restrict__ pos, int P,
                                              float* __restrict__ SP, int* __restrict__ xdst,
                                              int* __restrict__ wlb, int* __restrict__ wlL,
                                              int* __restrict__ wlR) {
  __shared__ int si;
  dev_sel(blockIdx.x, P, SCR, PAIR, pos, SP, xdst, wlb, wlL, wlR, &si);
}

// step: refresh this step's 2 pairs, then sel for next step (P=1 => final gather)
__global__ __launch_bounds__(256) void k_pairsel(int* __restrict__ wlb,
                                                 int* __restrict__ wlL,
                                                 int* __restrict__ wlR,
                                                 const float* __restrict__ GI,
                                                 const float* __restrict__ GHC,
                                                 const float* __restrict__ bhh,
                                                 const float* __restrict__ wfc,
                                                 const float* __restrict__ bfc,
                                                 float* __restrict__ PAIR,
                                                 float* __restrict__ SCR,
                                                 int* __restrict__ pos, int P,
                                                 float* __restrict__ SP,
                                                 int* __restrict__ xdst) {
  __shared__ float sb[256];
  __shared__ int si;
  int b = blockIdx.x;
  dev_pair(2 * b, wlb, wlL, wlR, GI, GHC, bhh, wfc, bfc[0], PAIR, SCR, sb);
  dev_pair(2 * b + 1, wlb, wlL, wlR, GI, GHC, bhh, wfc, bfc[0], PAIR, SCR, sb);
  dev_sel(b, P, SCR, PAIR, pos, SP, xdst, wlb, wlL, wlR, &si);
}

// ---------- final write ----------
__global__ __launch_bounds__(256) void k_writeout(const float* __restrict__ SC,
                                                  const float* __restrict__ LOSS,
                                                  float* __restrict__ out) {
  int idx = blockIdx.x * 256 + threadIdx.x;
  const int NS = B * (R + 1);
  if (idx < NS) {
    out[idx] = SC[idx];
  } else if (idx < NS + B * 16) {
    int r = idx - NS;
    int t = r & 15;
    out[idx] = (t == 14) ? 0.f : LOSS[r];
  }
}

extern "C" void kernel_launch(void* const* d_in, const int* in_sizes, int n_in,
                              void* d_out, int out_size, void* d_ws, size_t ws_size,
                              hipStream_t stream) {
  (void)in_sizes; (void)n_in; (void)out_size; (void)ws_size;
  const int* tokens = (const int*)d_in[0];
  const float* emb = (const float*)d_in[1];
  const float* W_ih = (const float*)d_in[2];
  const float* W_hh = (const float*)d_in[3];
  const float* b_ih = (const float*)d_in[4];
  const float* b_hh = (const float*)d_in[5];
  const float* w_fc = (const float*)d_in[6];
  const float* b_fc = (const float*)d_in[7];
  const float* Wq = (const float*)d_in[8];
  const float* bq = (const float*)d_in[9];
  const float* Wk = (const float*)d_in[10];
  const float* bk = (const float*)d_in[11];
  float* out = (float*)d_out;

  float* ws = (float*)d_ws;
  size_t o = 0;
  float* X = ws + o;     o += (size_t)B * 16 * E;
  float* GI = ws + o;    o += (size_t)B * 16 * K3;
  float* PAIR = ws + o;  o += (size_t)B * 16 * E;
  float* SCR = ws + o;   o += (size_t)B * 16;
  float* GHC = ws + o;   o += (size_t)NW0 * K3;
  float* KREL = ws + o;  o += (size_t)R * E;
  float* WQKT = ws + o;  o += (size_t)R * E;
  float* GT = ws + o;    o += (size_t)E * E;
  float* CQU = ws + o;   o += 1536;
  float* Y = ws + o;     o += (size_t)B * E;
  float* SP = ws + o;    o += (size_t)B * E;
  float* SC = ws + o;    o += (size_t)B * (R + 1);
  float* PART = ws + o;  o += (size_t)NSLC * B * E;
  float* LOSS = ws + o;  o += (size_t)B * 16;
  int* pos = (int*)(ws + o);  o += B * 16;
  int* wlb = (int*)(ws + o);  o += NW0;
  int* wlL = (int*)(ws + o);  o += NW0;
  int* wlR = (int*)(ws + o);  o += NW0;
  int* xdst = (int*)(ws + o); o += B;

  // ---- init ----
  k_embed<<<(B * S * E + 255) / 256, 256, 0, stream>>>(tokens, emb, X);
  k_initwl<<<8, 256, 0, stream>>>(pos, wlb, wlL, wlR);
  k_gemm<<<dim3(8, 16), 256, 0, stream>>>(emb, E, R, Wk, E, bk, KREL, E);
  k_nt<<<dim3(8, 16), 256, 0, stream>>>(KREL, R, Wq, WQKT);
  k_tt<<<dim3(8, 8), 256, 0, stream>>>(Wq, Wk, GT);
  k_smalls<<<7, 256, 0, stream>>>(KREL, Wq, Wk, bq, bk, CQU);
  k_gemm<<<dim3(24, 32), 256, 0, stream>>>(X, E, B * 16, W_ih, K3, b_ih, GI, K3);
  k_gh<<<dim3(24, 30), 256, 0, stream>>>(GI, wlb, wlL, NW0, W_hh, b_hh, GHC);
  k_pairc0<<<NW0, 256, 0, stream>>>(wlb, wlL, wlR, GI, GHC, b_hh, w_fc, b_fc, PAIR, SCR);
  k_sel0<<<B, 256, 0, stream>>>(SCR, PAIR, pos, 15, SP, xdst, wlb, wlL, wlR);

  // ---- 14 merge steps ----
  for (int t = 0; t < 14; ++t) {
    k_att<<<dim3(24, 2), 256, 0, stream>>>(SP, WQKT, GT, CQU, SC, Y);
    k_sm<<<B, 256, 0, stream>>>(SC, Y, SP, CQU, LOSS, t, 1);
    k_mg<<<dim3(8, 2, NSLC), 256, 0, stream>>>(SC, emb, SP, PART);
    k_gi<<<dim3(24, 2), 256, 0, stream>>>(PART, W_ih, b_ih, xdst, GI);
    k_gh<<<dim3(24, 4), 256, 0, stream>>>(GI, wlb, wlL, 2 * B, W_hh, b_hh, GHC);
    k_pairsel<<<B, 256, 0, stream>>>(wlb, wlL, wlR, GI, GHC, b_hh, w_fc, b_fc,
                                     PAIR, SCR, pos, 14 - t, SP, xdst);
  }

  // ---- final attention (SP already = final pair) ----
  k_att<<<dim3(24, 2), 256, 0, stream>>>(SP, WQKT, GT, CQU, SC, Y);
  k_sm<<<B, 256, 0, stream>>>(SC, Y, SP, CQU, LOSS, 15, 0);
  k_writeout<<<(B * (R + 1) + B * 16 + 255) / 256, 256, 0, stream>>>(SC, LOSS, out);
}

// Round 8
// 2958.503 us; speedup vs baseline: 2.0631x; 1.1188x over previous
//
#include <hip/hip_runtime.h>

#define B 128
#define S 16
#define E 512
#define R 1000
#define K3 1536
#define NW0 1920   // init worklist: 128 b * 15 pairs
#define NSLC 8     // K-slices for merged gemm (1000/8 = 125 exact)
#define SCALE 0.04419417382415922f

static __device__ __forceinline__ float sigm(float x) { return 1.f / (1.f + expf(-x)); }
static __device__ __forceinline__ float4 f40() { return make_float4(0.f, 0.f, 0.f, 0.f); }

static __device__ __forceinline__ float brsum(float v, float* sb) {
  int tid = threadIdx.x;
  sb[tid] = v; __syncthreads();
  for (int s = 128; s > 0; s >>= 1) {
    if (tid < s) sb[tid] += sb[tid + s];
    __syncthreads();
  }
  float r = sb[0]; __syncthreads();
  return r;
}
static __device__ __forceinline__ float brmax(float v, float* sb) {
  int tid = threadIdx.x;
  sb[tid] = v; __syncthreads();
  for (int s = 128; s > 0; s >>= 1) {
    if (tid < s) sb[tid] = fmaxf(sb[tid], sb[tid + s]);
    __syncthreads();
  }
  float r = sb[0]; __syncthreads();
  return r;
}

static __device__ __forceinline__ void fma16(const float (*__restrict__ As)[64],
                                             const float (*__restrict__ Ws)[64],
                                             float acc[4][4], int tx, int ty) {
#pragma unroll
  for (int k = 0; k < 16; ++k) {
    float4 a4 = *(const float4*)&As[k][ty * 4];
    float4 w4 = *(const float4*)&Ws[k][tx * 4];
    acc[0][0] = fmaf(a4.x, w4.x, acc[0][0]); acc[0][1] = fmaf(a4.x, w4.y, acc[0][1]);
    acc[0][2] = fmaf(a4.x, w4.z, acc[0][2]); acc[0][3] = fmaf(a4.x, w4.w, acc[0][3]);
    acc[1][0] = fmaf(a4.y, w4.x, acc[1][0]); acc[1][1] = fmaf(a4.y, w4.y, acc[1][1]);
    acc[1][2] = fmaf(a4.y, w4.z, acc[1][2]); acc[1][3] = fmaf(a4.y, w4.w, acc[1][3]);
    acc[2][0] = fmaf(a4.z, w4.x, acc[2][0]); acc[2][1] = fmaf(a4.z, w4.y, acc[2][1]);
    acc[2][2] = fmaf(a4.z, w4.z, acc[2][2]); acc[2][3] = fmaf(a4.z, w4.w, acc[2][3]);
    acc[3][0] = fmaf(a4.w, w4.x, acc[3][0]); acc[3][1] = fmaf(a4.w, w4.y, acc[3][1]);
    acc[3][2] = fmaf(a4.w, w4.z, acc[3][2]); acc[3][3] = fmaf(a4.w, w4.w, acc[3][3]);
  }
}

// ---------- init worklist ----------
__global__ __launch_bounds__(256) void k_initwl(int* __restrict__ pos,
                                                int* __restrict__ wlb,
                                                int* __restrict__ wlL,
                                                int* __restrict__ wlR) {
  int idx = blockIdx.x * 256 + threadIdx.x;
  if (idx < B * 16) pos[idx] = idx & 15;
  if (idx < NW0) {
    wlb[idx] = idx / 15; wlL[idx] = idx % 15; wlR[idx] = idx % 15 + 1;
  }
}

// ---------- generic GEMM: C[m,n] = sum_k A[row(m)*strideB+k]*W[n*E+k] + bias[n]
// row(m) = aidx ? aidx[m] : m   (aidx=tokens fuses the embed gather into A-stage)
__global__ __launch_bounds__(256) void k_gemm(const float* __restrict__ A, int strideB, int M,
                                              const int* __restrict__ aidx,
                                              const float* __restrict__ W, int N,
                                              const float* __restrict__ bias,
                                              float* __restrict__ C, int ldc) {
  __shared__ float As[16][64], Ws[16][64];
  int tid = threadIdx.x, mBase = blockIdx.y * 64, nBase = blockIdx.x * 64;
  int tx = tid & 15, ty = tid >> 4, li = tid & 63, lk = (tid >> 6) * 4;
  float acc[4][4] = {};
  int m = mBase + li;
  const float* Arow = nullptr;
  if (m < M) Arow = A + (size_t)(aidx ? aidx[m] : m) * strideB;
  int n = nBase + li;
  const float* Wrow = (n < N) ? W + (size_t)n * E : nullptr;
  float4 av = Arow ? *(const float4*)(Arow + lk) : f40();
  float4 wv = Wrow ? *(const float4*)(Wrow + lk) : f40();
  for (int k0 = 0; k0 < E; k0 += 16) {
    As[lk + 0][li] = av.x; As[lk + 1][li] = av.y; As[lk + 2][li] = av.z; As[lk + 3][li] = av.w;
    Ws[lk + 0][li] = wv.x; Ws[lk + 1][li] = wv.y; Ws[lk + 2][li] = wv.z; Ws[lk + 3][li] = wv.w;
    __syncthreads();
    if (k0 + 16 < E) {
      av = Arow ? *(const float4*)(Arow + k0 + 16 + lk) : f40();
      wv = Wrow ? *(const float4*)(Wrow + k0 + 16 + lk) : f40();
    }
    fma16(As, Ws, acc, tx, ty);
    __syncthreads();
  }
#pragma unroll
  for (int r = 0; r < 4; ++r) {
    int mm = mBase + ty * 4 + r;
    if (mm >= M) continue;
#pragma unroll
    for (int c = 0; c < 4; ++c) {
      int nn = nBase + tx * 4 + c;
      if (nn >= N) continue;
      C[(size_t)mm * ldc + nn] = acc[r][c] + (bias ? bias[nn] : 0.f);
    }
  }
}

// ---------- WQKT = KREL @ Wq (W k-major) ----------
__global__ __launch_bounds__(256) void k_nt(const float* __restrict__ A, int M,
                                            const float* __restrict__ W,
                                            float* __restrict__ C) {
  __shared__ float As[16][64], Ws[16][64];
  int tid = threadIdx.x, mBase = blockIdx.y * 64, nBase = blockIdx.x * 64;
  int tx = tid & 15, ty = tid >> 4, li = tid & 63, lk = (tid >> 6) * 4;
  int wr = tid >> 6;
  float acc[4][4] = {};
  int m = mBase + li;
  const float* Arow = (m < M) ? A + (size_t)m * E : nullptr;
  for (int k0 = 0; k0 < E; k0 += 16) {
    float4 av = Arow ? *(const float4*)(Arow + k0 + lk) : f40();
    As[lk + 0][li] = av.x; As[lk + 1][li] = av.y; As[lk + 2][li] = av.z; As[lk + 3][li] = av.w;
#pragma unroll
    for (int j = 0; j < 4; ++j)
      Ws[wr * 4 + j][li] = W[(size_t)(k0 + wr * 4 + j) * E + nBase + li];
    __syncthreads();
    fma16(As, Ws, acc, tx, ty);
    __syncthreads();
  }
#pragma unroll
  for (int r = 0; r < 4; ++r) {
    int mm = mBase + ty * 4 + r;
    if (mm >= M) continue;
#pragma unroll
    for (int c = 0; c < 4; ++c)
      C[(size_t)mm * E + nBase + tx * 4 + c] = acc[r][c];
  }
}

// ---------- G = Wq^T @ Wk ----------
__global__ __launch_bounds__(256) void k_tt(const float* __restrict__ A,
                                            const float* __restrict__ Bw,
                                            float* __restrict__ C) {
  __shared__ float As[16][64], Ws[16][64];
  int tid = threadIdx.x, mBase = blockIdx.y * 64, nBase = blockIdx.x * 64;
  int tx = tid & 15, ty = tid >> 4, li = tid & 63;
  int wr = tid >> 6;
  float acc[4][4] = {};
  for (int k0 = 0; k0 < E; k0 += 16) {
#pragma unroll
    for (int j = 0; j < 4; ++j) {
      As[wr * 4 + j][li] = A[(size_t)(k0 + wr * 4 + j) * E + mBase + li];
      Ws[wr * 4 + j][li] = Bw[(size_t)(k0 + wr * 4 + j) * E + nBase + li];
    }
    __syncthreads();
    fma16(As, Ws, acc, tx, ty);
    __syncthreads();
  }
#pragma unroll
  for (int r = 0; r < 4; ++r)
#pragma unroll
    for (int c = 0; c < 4; ++c)
      C[(size_t)(mBase + ty * 4 + r) * E + nBase + tx * 4 + c] = acc[r][c];
}

// ---------- folded bias terms ----------
__global__ __launch_bounds__(256) void k_smalls(const float* __restrict__ KREL,
                                                const float* __restrict__ Wq,
                                                const float* __restrict__ Wk,
                                                const float* __restrict__ bq,
                                                const float* __restrict__ bk,
                                                float* __restrict__ CQU) {
  __shared__ float sb[256];
  int bid = blockIdx.x, tid = threadIdx.x;
  if (bid < 4) {
    int j = bid * 256 + tid;
    if (j < R) {
      float s = 0.f;
      const float* kr = KREL + (size_t)j * E;
      for (int f = 0; f < E; ++f) s += bq[f] * kr[f];
      CQU[j] = SCALE * s;
    }
  } else if (bid < 6) {
    int e = (bid - 4) * 256 + tid;
    float s = 0.f;
    for (int f = 0; f < E; ++f) s += bq[f] * Wk[(size_t)f * E + e] + bk[f] * Wq[(size_t)f * E + e];
    CQU[1000 + e] = SCALE * s;
  } else {
    float part = 0.f;
    for (int f = tid; f < E; f += 256) part += bq[f] * bk[f];
    float s = brsum(part, sb);
    if (tid == 0) CQU[1512] = SCALE * s;
  }
}

// ---------- h1 for worklist entries (materialized ONCE — 1x expf) ----------
__global__ __launch_bounds__(256) void k_h1c(const int* __restrict__ wlb,
                                             const int* __restrict__ wlL,
                                             const float* __restrict__ GI,
                                             const float* __restrict__ bhh,
                                             float* __restrict__ H1C) {
  int w = blockIdx.x;
  const float* gi = GI + (size_t)(wlb[w] * 16 + wlL[w]) * K3;
  float* h = H1C + (size_t)w * E;
  for (int e = threadIdx.x; e < E; e += 256) {
    float r = sigm(gi[e] + bhh[e]);
    float z = sigm(gi[E + e] + bhh[E + e]);
    float n = tanhf(gi[2 * E + e] + r * bhh[2 * E + e]);
    h[e] = (1.f - z) * n;
  }
}

// ---------- GI step gemm: A = sum_s PART[s]; C row = xdst[m] ----------
__global__ __launch_bounds__(256) void k_gi(const float* __restrict__ PART,
                                            const float* __restrict__ Wih,
                                            const float* __restrict__ bih,
                                            const int* __restrict__ xdst,
                                            float* __restrict__ GI) {
  __shared__ float As[16][64], Ws[16][64];
  int tid = threadIdx.x, mBase = blockIdx.y * 64, nBase = blockIdx.x * 64;
  int tx = tid & 15, ty = tid >> 4, li = tid & 63, lk = (tid >> 6) * 4;
  float acc[4][4] = {};
  int m = mBase + li;  // < 128 always
  const float* Wrow = Wih + (size_t)(nBase + li) * E;  // N=1536 exact
  for (int k0 = 0; k0 < E; k0 += 16) {
    float4 a = f40();
#pragma unroll
    for (int s = 0; s < NSLC; ++s) {
      float4 p = *(const float4*)(PART + ((size_t)(s * B + m)) * E + k0 + lk);
      a.x += p.x; a.y += p.y; a.z += p.z; a.w += p.w;
    }
    As[lk + 0][li] = a.x; As[lk + 1][li] = a.y; As[lk + 2][li] = a.z; As[lk + 3][li] = a.w;
    float4 wv = *(const float4*)(Wrow + k0 + lk);
    Ws[lk + 0][li] = wv.x; Ws[lk + 1][li] = wv.y; Ws[lk + 2][li] = wv.z; Ws[lk + 3][li] = wv.w;
    __syncthreads();
    fma16(As, Ws, acc, tx, ty);
    __syncthreads();
  }
#pragma unroll
  for (int r = 0; r < 4; ++r) {
    size_t crow = (size_t)xdst[mBase + ty * 4 + r] * K3;
#pragma unroll
    for (int c = 0; c < 4; ++c) {
      int nn = nBase + tx * 4 + c;
      GI[crow + nn] = acc[r][c] + bih[nn];
    }
  }
}

// ---------- fused attention gemm: cols 0..999 -> SC, 1000..1511 -> Y ----------
__global__ __launch_bounds__(256) void k_att(const float* __restrict__ SP,
                                             const float* __restrict__ WQKT,
                                             const float* __restrict__ GT,
                                             const float* __restrict__ CQU,
                                             float* __restrict__ SC,
                                             float* __restrict__ Y) {
  __shared__ float As[16][64], Ws[16][64];
  int tid = threadIdx.x, mBase = blockIdx.y * 64, nBase = blockIdx.x * 64;
  int tx = tid & 15, ty = tid >> 4, li = tid & 63, lk = (tid >> 6) * 4;
  float acc[4][4] = {};
  int m = mBase + li;  // < 128
  const float* Arow = SP + (size_t)m * E;
  int n = nBase + li;
  const float* Wrow = (n < 1000) ? WQKT + (size_t)n * E
                                 : (n < 1512 ? GT + (size_t)(n - 1000) * E : nullptr);
  float4 av = *(const float4*)(Arow + lk);
  float4 wv = Wrow ? *(const float4*)(Wrow + lk) : f40();
  for (int k0 = 0; k0 < E; k0 += 16) {
    As[lk + 0][li] = av.x; As[lk + 1][li] = av.y; As[lk + 2][li] = av.z; As[lk + 3][li] = av.w;
    Ws[lk + 0][li] = wv.x; Ws[lk + 1][li] = wv.y; Ws[lk + 2][li] = wv.z; Ws[lk + 3][li] = wv.w;
    __syncthreads();
    if (k0 + 16 < E) {
      av = *(const float4*)(Arow + k0 + 16 + lk);
      wv = Wrow ? *(const float4*)(Wrow + k0 + 16 + lk) : f40();
    }
    fma16(As, Ws, acc, tx, ty);
    __syncthreads();
  }
#pragma unroll
  for (int r = 0; r < 4; ++r) {
    int mm = mBase + ty * 4 + r;
#pragma unroll
    for (int c = 0; c < 4; ++c) {
      int nn = nBase + tx * 4 + c;
      if (nn >= 1512) continue;
      float v = acc[r][c] * SCALE + CQU[nn];
      if (nn < 1000) SC[(size_t)mm * (R + 1) + nn] = v;
      else Y[(size_t)mm * E + (nn - 1000)] = v;
    }
  }
}

// ---------- softmax stats + entropy loss (NO prob writeback) ----------
__global__ __launch_bounds__(256) void k_sm(float* __restrict__ SC,
                                            const float* __restrict__ Y,
                                            const float* __restrict__ SP,
                                            const float* __restrict__ CQU,
                                            float* __restrict__ STAT,
                                            float* __restrict__ LOSS, int t) {
  __shared__ float sb[256];
  int b = blockIdx.x, tid = threadIdx.x;
  const float* y = Y + (size_t)b * E;
  const float* sp = SP + (size_t)b * E;
  float part = 0.f;
  for (int e = tid; e < E; e += 256) part += y[e] * sp[e];
  float last = brsum(part, sb) + CQU[1512];
  float* s = SC + (size_t)b * (R + 1);
  if (tid == 0) s[R] = last;
  __syncthreads();
  float mx = -1e30f;
  for (int j = tid; j <= R; j += 256) mx = fmaxf(mx, s[j]);
  mx = brmax(mx, sb);
  float z = 0.f, s1 = 0.f;
  for (int j = tid; j <= R; j += 256) {
    float sj = s[j];
    float e = expf(sj - mx);
    z += e; s1 += e * sj;
  }
  z = brsum(z, sb);
  s1 = brsum(s1, sb);
  if (tid == 0) {
    LOSS[b * 16 + t] = mx + logf(z) - s1 / z;
    STAT[2 * b] = mx;
    STAT[2 * b + 1] = 1.f / z;
  }
}

// ---------- merged split-K; prob computed on the fly from raw SC + STAT ----------
__global__ __launch_bounds__(256) void k_mg(const float* __restrict__ SC,
                                            const float* __restrict__ STAT,
                                            const float* __restrict__ emb,
                                            const float* __restrict__ SP,
                                            float* __restrict__ PART) {
  __shared__ float As[16][64], Ws[16][64];
  int tid = threadIdx.x;
  int nBase = blockIdx.x * 64, mBase = blockIdx.y * 64, slice = blockIdx.z;
  int kbeg = slice * 125, kend = kbeg + 125;
  int tx = tid & 15, ty = tid >> 4, li = tid & 63, lk = (tid >> 6) * 4;
  int wr = tid >> 6;
  float acc[4][4] = {};
  int m = mBase + li;
  float mx = STAT[2 * m], inv = STAT[2 * m + 1];
  for (int k0 = kbeg; k0 < kend; k0 += 16) {
    float a4[4];
#pragma unroll
    for (int j = 0; j < 4; ++j) {
      int kk = k0 + lk + j;
      a4[j] = (kk < kend) ? expf(SC[(size_t)m * (R + 1) + kk] - mx) * inv : 0.f;
    }
    As[lk + 0][li] = a4[0]; As[lk + 1][li] = a4[1]; As[lk + 2][li] = a4[2]; As[lk + 3][li] = a4[3];
#pragma unroll
    for (int j = 0; j < 4; ++j) {
      int kk = k0 + wr * 4 + j;
      Ws[wr * 4 + j][li] = (kk < kend) ? emb[(size_t)kk * E + nBase + li] : 0.f;
    }
    __syncthreads();
    fma16(As, Ws, acc, tx, ty);
    __syncthreads();
  }
  float* pt = PART + (size_t)slice * B * E;
#pragma unroll
  for (int r = 0; r < 4; ++r) {
    int mm = mBase + ty * 4 + r;
    float probR = 0.f;
    if (slice == 0)
      probR = expf(SC[(size_t)mm * (R + 1) + R] - STAT[2 * mm]) * STAT[2 * mm + 1];
#pragma unroll
    for (int c = 0; c < 4; ++c) {
      int nn = nBase + tx * 4 + c;
      float v = acc[r][c];
      if (slice == 0) v += probR * SP[(size_t)mm * E + nn];
      pt[(size_t)mm * E + nn] = v;
    }
  }
}

// ---------- pair body (reads precomputed H1C) ----------
static __device__ void dev_pair(int w, const int* wlb, const int* wlL, const int* wlR,
                                const float* GI, const float* GHC, const float* H1C,
                                const float* wfc, float bfc0,
                                float* PAIR, float* SCR, float* sb) {
  int tid = threadIdx.x;
  int b = wlb[w], ls = wlL[w], rs = wlR[w];
  const float* gir = GI + (size_t)(b * 16 + rs) * K3;
  const float* gh = GHC + (size_t)w * K3;
  const float* h = H1C + (size_t)w * E;
  float* p = PAIR + (size_t)(b * 16 + ls) * E;
  float part = 0.f;
  for (int e = tid; e < E; e += 256) {
    float r = sigm(gir[e] + gh[e]);
    float z = sigm(gir[E + e] + gh[E + e]);
    float n = tanhf(gir[2 * E + e] + r * gh[2 * E + e]);
    float pv = (1.f - z) * n + z * h[e];
    p[e] = pv;
    part += pv * wfc[e];
  }
  float d = brsum(part, sb);
  if (tid == 0) SCR[b * 16 + ls] = sigm(d + bfc0);
}

static __device__ void dev_sel(int b, int Pn, const float* SCR, const float* PAIR,
                               int* pos, float* SP, int* xdst,
                               int* wlb, int* wlL, int* wlR, int* s_m) {
  int tid = threadIdx.x;
  if (tid == 0) {
    int L = Pn + 1;
    int lp[16];
    for (int i = 0; i < L; ++i) lp[i] = pos[b * 16 + i];
    float best = -1e30f; int sel = 0;
    for (int i = 0; i < Pn; ++i) {
      float v = SCR[b * 16 + lp[i]];
      if (v > best) { best = v; sel = i; }
    }
    int r1i = (sel + 2 < L) ? sel + 2 : L - 1;
    int l1 = lp[sel], r1 = lp[r1i];
    int l0 = (sel > 0) ? lp[sel - 1] : l1;
    int r0 = (sel > 0) ? lp[sel] : r1;
    wlb[2 * b] = b;     wlL[2 * b] = l0;     wlR[2 * b] = r0;
    wlb[2 * b + 1] = b; wlL[2 * b + 1] = l1; wlR[2 * b + 1] = r1;
    xdst[b] = b * 16 + lp[sel];
    for (int i = sel + 1; i < L - 1; ++i) pos[b * 16 + i] = lp[i + 1];
    *s_m = lp[sel];
  }
  __syncthreads();
  int ms = *s_m;
  const float* src = PAIR + (size_t)(b * 16 + ms) * E;
  float* dst = SP + (size_t)b * E;
  for (int e = tid; e < E; e += 256) dst[e] = src[e];
}

__global__ __launch_bounds__(256) void k_pairc0(const int* __restrict__ wlb,
                                                const int* __restrict__ wlL,
                                                const int* __restrict__ wlR,
                                                const float* __restrict__ GI,
                                                const float* __restrict__ GHC,
                                                const float* __restrict__ H1C,
                                                const float* __restrict__ wfc,
                                                const float* __restrict__ bfc,
                                                float* __restrict__ PAIR,
                                                float* __restrict__ SCR) {
  __shared__ float sb[256];
  dev_pair(blockIdx.x, wlb, wlL, wlR, GI, GHC, H1C, wfc, bfc[0], PAIR, SCR, sb);
}

__global__ __launch_bounds__(256) void k_sel0(const float* __restrict__ SCR,
                                              const float* __restrict__ PAIR,
                                              int* __restrict__ pos, int P,
                                              float* __restrict__ SP, int* __restrict__ xdst,
                                              int* __restrict__ wlb, int* __restrict__ wlL,
                                              int* __restrict__ wlR) {
  __shared__ int si;
  dev_sel(blockIdx.x, P, SCR, PAIR, pos, SP, xdst, wlb, wlL, wlR, &si);
}

__global__ __launch_bounds__(256) void k_pairsel(int* __restrict__ wlb,
                                                 int* __restrict__ wlL,
                                                 int* __restrict__ wlR,
                                                 const float* __restrict__ GI,
                                                 const float* __restrict__ GHC,
                                                 const float* __restrict__ H1C,
                                                 const float* __restrict__ wfc,
                                                 const float* __restrict__ bfc,
                                                 float* __restrict__ PAIR,
                                                 float* __restrict__ SCR,
                                                 int* __restrict__ pos, int P,
                                                 float* __restrict__ SP,
                                                 int* __restrict__ xdst) {
  __shared__ float sb[256];
  __shared__ int si;
  int b = blockIdx.x;
  dev_pair(2 * b, wlb, wlL, wlR, GI, GHC, H1C, wfc, bfc[0], PAIR, SCR, sb);
  dev_pair(2 * b + 1, wlb, wlL, wlR, GI, GHC, H1C, wfc, bfc[0], PAIR, SCR, sb);
  dev_sel(b, P, SCR, PAIR, pos, SP, xdst, wlb, wlL, wlR, &si);
}

// ---------- final write ----------
__global__ __launch_bounds__(256) void k_writeout(const float* __restrict__ SC,
                                                  const float* __restrict__ LOSS,
                                                  float* __restrict__ out) {
  int idx = blockIdx.x * 256 + threadIdx.x;
  const int NS = B * (R + 1);
  if (idx < NS) {
    out[idx] = SC[idx];
  } else if (idx < NS + B * 16) {
    int r = idx - NS;
    int t = r & 15;
    out[idx] = (t == 14) ? 0.f : LOSS[r];
  }
}

extern "C" void kernel_launch(void* const* d_in, const int* in_sizes, int n_in,
                              void* d_out, int out_size, void* d_ws, size_t ws_size,
                              hipStream_t stream) {
  (void)in_sizes; (void)n_in; (void)out_size; (void)ws_size;
  const int* tokens = (const int*)d_in[0];
  const float* emb = (const float*)d_in[1];
  const float* W_ih = (const float*)d_in[2];
  const float* W_hh = (const float*)d_in[3];
  const float* b_ih = (const float*)d_in[4];
  const float* b_hh = (const float*)d_in[5];
  const float* w_fc = (const float*)d_in[6];
  const float* b_fc = (const float*)d_in[7];
  const float* Wq = (const float*)d_in[8];
  const float* bq = (const float*)d_in[9];
  const float* Wk = (const float*)d_in[10];
  const float* bk = (const float*)d_in[11];
  float* out = (float*)d_out;

  float* ws = (float*)d_ws;
  size_t o = 0;
  float* GI = ws + o;    o += (size_t)B * 16 * K3;
  float* PAIR = ws + o;  o += (size_t)B * 16 * E;
  float* SCR = ws + o;   o += (size_t)B * 16;
  float* H1C = ws + o;   o += (size_t)NW0 * E;
  float* GHC = ws + o;   o += (size_t)NW0 * K3;
  float* KREL = ws + o;  o += (size_t)R * E;
  float* WQKT = ws + o;  o += (size_t)R * E;
  float* GT = ws + o;    o += (size_t)E * E;
  float* CQU = ws + o;   o += 1536;
  float* Y = ws + o;     o += (size_t)B * E;
  float* SP = ws + o;    o += (size_t)B * E;
  float* SC = ws + o;    o += (size_t)B * (R + 1);
  float* PART = ws + o;  o += (size_t)NSLC * B * E;
  float* STAT = ws + o;  o += 2 * B;
  float* LOSS = ws + o;  o += (size_t)B * 16;
  int* pos = (int*)(ws + o);  o += B * 16;
  int* wlb = (int*)(ws + o);  o += NW0;
  int* wlL = (int*)(ws + o);  o += NW0;
  int* wlR = (int*)(ws + o);  o += NW0;
  int* xdst = (int*)(ws + o); o += B;

  // ---- init ----
  k_initwl<<<8, 256, 0, stream>>>(pos, wlb, wlL, wlR);
  k_gemm<<<dim3(8, 16), 256, 0, stream>>>(emb, E, R, nullptr, Wk, E, bk, KREL, E);
  k_nt<<<dim3(8, 16), 256, 0, stream>>>(KREL, R, Wq, WQKT);
  k_tt<<<dim3(8, 8), 256, 0, stream>>>(Wq, Wk, GT);
  k_smalls<<<7, 256, 0, stream>>>(KREL, Wq, Wk, bq, bk, CQU);
  // init GI with embed fused into A-stage (aidx = tokens)
  k_gemm<<<dim3(24, 32), 256, 0, stream>>>(emb, E, B * 16, tokens, W_ih, K3, b_ih, GI, K3);
  k_h1c<<<NW0, 256, 0, stream>>>(wlb, wlL, GI, b_hh, H1C);
  k_gemm<<<dim3(24, 30), 256, 0, stream>>>(H1C, E, NW0, nullptr, W_hh, K3, b_hh, GHC, K3);
  k_pairc0<<<NW0, 256, 0, stream>>>(wlb, wlL, wlR, GI, GHC, H1C, w_fc, b_fc, PAIR, SCR);
  k_sel0<<<B, 256, 0, stream>>>(SCR, PAIR, pos, 15, SP, xdst, wlb, wlL, wlR);

  // ---- 14 merge steps ----
  for (int t = 0; t < 14; ++t) {
    k_att<<<dim3(24, 2), 256, 0, stream>>>(SP, WQKT, GT, CQU, SC, Y);
    k_sm<<<B, 256, 0, stream>>>(SC, Y, SP, CQU, STAT, LOSS, t);
    k_mg<<<dim3(8, 2, NSLC), 256, 0, stream>>>(SC, STAT, emb, SP, PART);
    k_gi<<<dim3(24, 2), 256, 0, stream>>>(PART, W_ih, b_ih, xdst, GI);
    k_h1c<<<2 * B, 256, 0, stream>>>(wlb, wlL, GI, b_hh, H1C);
    k_gemm<<<dim3(24, 4), 256, 0, stream>>>(H1C, E, 2 * B, nullptr, W_hh, K3, b_hh, GHC, K3);
    k_pairsel<<<B, 256, 0, stream>>>(wlb, wlL, wlR, GI, GHC, H1C, w_fc, b_fc,
                                     PAIR, SCR, pos, 14 - t, SP, xdst);
  }

  // ---- final attention (SP already = final pair) ----
  k_att<<<dim3(24, 2), 256, 0, stream>>>(SP, WQKT, GT, CQU, SC, Y);
  k_sm<<<B, 256, 0, stream>>>(SC, Y, SP, CQU, STAT, LOSS, 15);
  k_writeout<<<(B * (R + 1) + B * 16 + 255) / 256, 256, 0, stream>>>(SC, LOSS, out);
}